// Round 1
// baseline (277.608 us; speedup 1.0000x reference)
//
#include <hip/hip_runtime.h>
#include <hip/hip_bf16.h>

typedef __bf16 bf16_t;
typedef __bf16 bf16x8 __attribute__((ext_vector_type(8)));
typedef float  floatx4 __attribute__((ext_vector_type(4)));

#define BQ 16
#define NTOK 2048
#define DIM 256
#define HD 64

// ---------------- Kernel 0: W -> W^T bf16, + zero out-accumulator & rowsums ----------------
__global__ __launch_bounds__(256) void k_prep(const float* __restrict__ Wq,
                                              const float* __restrict__ Wk,
                                              const float* __restrict__ Wv,
                                              bf16_t* __restrict__ wt,
                                              float* __restrict__ outz,
                                              float* __restrict__ rsz) {
    int o = blockIdx.x * 256 + threadIdx.x;   // grid 1024 -> o < 262144
    if (o < 49152) {
        int w = o >> 14;
        int r = o & 16383;
        int h = r >> 8;
        int d = r & 255;
        const float* W = (w == 0) ? Wq : ((w == 1) ? Wk : Wv);
        wt[o] = (bf16_t)W[d * 64 + h];
    }
    // zero out (524288 float4) + rs (8192 float4)
    float4 z = make_float4(0.f, 0.f, 0.f, 0.f);
    for (int u = o; u < 532480; u += 262144) {
        if (u < 524288) ((float4*)outz)[u] = z;
        else            ((float4*)rsz)[u - 524288] = z;
    }
}

// ---------------- Kernel 1: QKV projection (64 tokens/block, 512 blocks) ----------------
#define XS 264
__global__ __launch_bounds__(256) void k_qkv(const float* __restrict__ x,
                                             const bf16_t* __restrict__ wt,
                                             const float* __restrict__ bq,
                                             const float* __restrict__ bk,
                                             const float* __restrict__ bv,
                                             bf16_t* __restrict__ qb,
                                             bf16_t* __restrict__ kb,
                                             bf16_t* __restrict__ vt) {
    __shared__ bf16_t x_ls[64 * XS];
    __shared__ bf16_t vt_ls[64 * 72];

    int b  = blockIdx.x >> 5;
    int t0 = (blockIdx.x & 31) << 6;
    int t  = threadIdx.x;
    int lane = t & 63;
    int w    = t >> 6;
    int m_   = lane & 15;
    int q4   = lane >> 4;

    for (int tau = t; tau < 4096; tau += 256) {
        int row = tau >> 6, ch = tau & 63;
        float4 v = ((const float4*)x)[(size_t)(b * NTOK + t0 + row) * 64 + ch];
        bf16_t tmp[4] = {(bf16_t)v.x, (bf16_t)v.y, (bf16_t)v.z, (bf16_t)v.w};
        *(uint2*)(&x_ls[row * XS + ch * 4]) = *(uint2*)tmp;
    }
    __syncthreads();

    for (int wi = 0; wi < 3; ++wi) {
        const bf16_t* wtw = wt + wi * 16384;
        floatx4 acc[4];
        #pragma unroll
        for (int mt = 0; mt < 4; ++mt) acc[mt] = floatx4{0.f, 0.f, 0.f, 0.f};

        #pragma unroll
        for (int ks = 0; ks < 8; ++ks) {
            bf16x8 bfrag = *(const bf16x8*)(wtw + (16 * w + m_) * 256 + ks * 32 + q4 * 8);
            #pragma unroll
            for (int mt = 0; mt < 4; ++mt) {
                bf16x8 afrag = *(const bf16x8*)(&x_ls[(16 * mt + m_) * XS + ks * 32 + q4 * 8]);
                acc[mt] = __builtin_amdgcn_mfma_f32_16x16x32_bf16(afrag, bfrag, acc[mt], 0, 0, 0);
            }
        }
        const float* bias_p = (wi == 0) ? bq : ((wi == 1) ? bk : bv);
        float bias = bias_p[16 * w + m_];
        float scale = (wi == 0) ? 0.125f : 1.0f;   // fold H^-0.5 into q (exact pow2)

        if (wi < 2) {
            bf16_t* dst = (wi == 0) ? qb : kb;
            #pragma unroll
            for (int mt = 0; mt < 4; ++mt)
                #pragma unroll
                for (int r = 0; r < 4; ++r) {
                    int tok = t0 + 16 * mt + 4 * q4 + r;
                    dst[(size_t)(b * NTOK + tok) * 64 + 16 * w + m_] = (bf16_t)((acc[mt][r] + bias) * scale);
                }
        } else {
            #pragma unroll
            for (int mt = 0; mt < 4; ++mt)
                #pragma unroll
                for (int r = 0; r < 4; ++r)
                    vt_ls[(16 * w + m_) * 72 + 16 * mt + 4 * q4 + r] = (bf16_t)(acc[mt][r] + bias);
            __syncthreads();
            for (int tau = t; tau < 512; tau += 256) {
                int h = tau >> 3, ch = tau & 7;
                uint4 val = *(const uint4*)(&vt_ls[h * 72 + ch * 8]);
                *(uint4*)(vt + (size_t)(b * 64 + h) * NTOK + t0 + ch * 8) = val;
            }
        }
    }
}

// ---------------- Kernel 2: fused attention, 64x64 frame (62x62 interior), 512 threads ----------------
#define SA 68     // A_ls fp32 stride (cols 64..67 zero pad, 16B-aligned rows)
#define SP 72     // bf16 LDS stride
#define RINT 62
#define L2E 1.44269504f

static __device__ __forceinline__ bf16x8 as_bf16x8(uint4 u) {
    union { uint4 a; bf16x8 b; } c; c.a = u; return c.b;
}

__global__ __launch_bounds__(512, 6) void k_attn(const bf16_t* __restrict__ qb,
                                                 const bf16_t* __restrict__ kb,
                                                 const bf16_t* __restrict__ vt,
                                                 const float* __restrict__ conv_w,
                                                 const float* __restrict__ conv_b,
                                                 float* __restrict__ outp,
                                                 float* __restrict__ rsg) {
    __shared__ bf16_t k_ls[64 * SP];   // 9216 B  [frame col j][ch]
    __shared__ bf16_t v_ls[64 * SP];   // 9216 B  [h][k], k = global_col - c0; k>=62 zero
    __shared__ bf16_t p_ls[64 * SP];   // 9216 B  [i][k]; rows 0,63 & k>=62 zero
    __shared__ float  A_ls[64 * SA];   // 17408 B  -> total 45056 B -> 3 blocks/CU

    int b  = blockIdx.z;
    int r0 = blockIdx.x * RINT;
    int it_beg = (int)(blockIdx.y * 34) >> 2;         // chunks {8,9,8,9} iters
    int it_end = (int)((blockIdx.y + 1) * 34) >> 2;

    int t = threadIdx.x, lane = t & 63, w = t >> 6;
    int m_ = lane & 15, q4 = lane >> 4;
    int wtj = w & 3;             // col tile 0..3
    int wti = (w >> 2) << 1;     // row tile base {0,2}

    const uint* vt32 = (const uint*)vt + (size_t)b * 64 * 1024;

    // v prefetch task mapping (1984 uint loads over 4 rounds)
    int vh[4], vc[4];
    #pragma unroll
    for (int j = 0; j < 4; ++j) { int tau = t + 512 * j; vh[j] = tau / 31; vc[j] = tau % 31; }

    uint4 kreg;
    uint  vreg[4];
    auto prefetch = [&](int c0) {
        {
            int row = t >> 3, ch = t & 7;
            int g = c0 - 1 + row;
            uint4 val = make_uint4(0u, 0u, 0u, 0u);
            if (g >= 0 && g < NTOK)
                val = *(const uint4*)(kb + (size_t)(b * NTOK + g) * 64 + ch * 8);
            kreg = val;
        }
        #pragma unroll
        for (int j = 0; j < 4; ++j) {
            if (t + 512 * j < 1984) {
                int n = c0 + 2 * vc[j];
                uint val = 0u;
                if (n < NTOK) val = vt32[vh[j] * 1024 + (n >> 1)];
                vreg[j] = val;
            }
        }
    };

    prefetch(it_beg * RINT);

    // conv weights, ln2-folded so sigmoid uses exp2 directly
    float cw[9];
    #pragma unroll
    for (int i = 0; i < 9; ++i) cw[i] = conv_w[i] * L2E;
    float cb = conv_b[0] * L2E;

    // rim mask as multiplicative constant (frame col k = 4*gq+x valid iff <= 61)
    float msk[4];
    #pragma unroll
    for (int x = 0; x < 4; ++x) msk[x] = (4 * (t & 15) + x <= 61) ? 1.f : 0.f;

    // Q fragments -> registers (frame rows 16*(wti+p)+m_, loaded once)
    bf16x8 qreg[2][2];
    #pragma unroll
    for (int p = 0; p < 2; ++p) {
        int g = r0 - 1 + 16 * (wti + p) + m_;
        #pragma unroll
        for (int ks = 0; ks < 2; ++ks) {
            uint4 val = make_uint4(0u, 0u, 0u, 0u);
            if (g >= 0 && g < NTOK)
                val = *(const uint4*)(qb + (size_t)(b * NTOK + g) * 64 + ks * 32 + q4 * 8);
            qreg[p][ks] = as_bf16x8(val);
        }
    }

    // one-time zero inits
    for (int u = t; u < 2304; u += 512) ((uint*)p_ls)[u] = 0u;              // whole p_ls
    if (t < 320) {                                                          // v_ls pad cols 62..71
        int h = t / 5, c = 62 + 2 * (t % 5);
        *(uint*)(&v_ls[h * SP + c]) = 0u;
    }
    if (t < 256) A_ls[(t >> 2) * SA + 64 + (t & 3)] = 0.f;                  // A_ls col pad

    floatx4 accO[2];
    accO[0] = floatx4{0.f, 0.f, 0.f, 0.f};
    accO[1] = floatx4{0.f, 0.f, 0.f, 0.f};
    float rs[2] = {0.f, 0.f};

    int i0 = (t >> 4) + 1;     // conv row, round 0 (1..32); round 1 adds 32
    int gq = t & 15;           // quad col group 0..15
    int cvoff = (i0 - 1) * SA + 4 * gq;

    for (int itg = it_beg; itg < it_end; ++itg) {
        // ---- regs -> LDS (k_ls, v_ls) ----
        {
            int row = t >> 3, ch = t & 7;
            *(uint4*)(&k_ls[row * SP + ch * 8]) = kreg;
            #pragma unroll
            for (int j = 0; j < 4; ++j)
                if (t + 512 * j < 1984)
                    *(uint*)(&v_ls[vh[j] * SP + 2 * vc[j]]) = vreg[j];
        }
        __syncthreads();

        // ---- QK^T: 16 tiles, 2 per wave, K=64, Q in registers ----
        #pragma unroll
        for (int p = 0; p < 2; ++p) {
            floatx4 a = floatx4{0.f, 0.f, 0.f, 0.f};
            #pragma unroll
            for (int ks = 0; ks < 2; ++ks) {
                bf16x8 bfr = *(const bf16x8*)(&k_ls[(16 * wtj + m_) * SP + ks * 32 + q4 * 8]);
                a = __builtin_amdgcn_mfma_f32_16x16x32_bf16(qreg[p][ks], bfr, a, 0, 0, 0);
            }
            int rbase = 16 * (wti + p) + 4 * q4;
            #pragma unroll
            for (int r = 0; r < 4; ++r)
                A_ls[(rbase + r) * SA + 16 * wtj + m_] = a[r];
        }
        __syncthreads();

        // issue next iter's global loads; latency overlaps conv below
        if (itg + 1 < it_end) prefetch((itg + 1) * RINT);

        // ---- conv + sigmoid + relu + expm1 (1x4 quads, 992 tasks over 2 rounds) ----
        #pragma unroll
        for (int round = 0; round < 2; ++round) {
            if (round == 0 || t < 480) {
                const float* base = &A_ls[cvoff + round * (32 * SA)];
                float a0[6], a1[6], a2[6];
                *(float4*)(a0)     = *(const float4*)(base);
                *(float2*)(a0 + 4) = *(const float2*)(base + 4);
                *(float4*)(a1)     = *(const float4*)(base + SA);
                *(float2*)(a1 + 4) = *(const float2*)(base + SA + 4);
                *(float4*)(a2)     = *(const float4*)(base + 2 * SA);
                *(float2*)(a2 + 4) = *(const float2*)(base + 2 * SA + 4);
                float esum = 0.f;
                bf16_t quad[4];
                #pragma unroll
                for (int x = 0; x < 4; ++x) {
                    float conv = cb
                        + cw[0] * a0[x] + cw[1] * a0[x + 1] + cw[2] * a0[x + 2]
                        + cw[3] * a1[x] + cw[4] * a1[x + 1] + cw[5] * a1[x + 2]
                        + cw[6] * a2[x] + cw[7] * a2[x + 1] + cw[8] * a2[x + 2];
                    float sig = __builtin_amdgcn_rcpf(1.f + __builtin_amdgcn_exp2f(-conv));
                    float s = fmaxf(a1[x + 1] - sig, 0.f);
                    float ev = (__builtin_amdgcn_exp2f(s * L2E) - 1.f) * msk[x];
                    quad[x] = (bf16_t)ev;
                    esum += ev;
                }
                rs[round] += esum;
                *(uint2*)(&p_ls[(i0 + round * 32) * SP + 4 * gq]) = *(uint2*)quad;
            }
        }
        __syncthreads();

        // ---- PV: O[64x64] += P @ V, 2 tiles per wave ----
        #pragma unroll
        for (int ks = 0; ks < 2; ++ks) {
            bf16x8 bfr = *(const bf16x8*)(&v_ls[(16 * wtj + m_) * SP + ks * 32 + q4 * 8]);
            #pragma unroll
            for (int p = 0; p < 2; ++p) {
                bf16x8 af = *(const bf16x8*)(&p_ls[(16 * (wti + p) + m_) * SP + ks * 32 + q4 * 8]);
                accO[p] = __builtin_amdgcn_mfma_f32_16x16x32_bf16(af, bfr, accO[p], 0, 0, 0);
            }
        }
        __syncthreads();
    }

    // ---- epilogue: rowsum via 16-lane shfl reduce -> atomic ----
    float s0 = rs[0], s1 = rs[1];
    #pragma unroll
    for (int d = 1; d < 16; d <<= 1) {
        s0 += __shfl_xor(s0, d);
        s1 += __shfl_xor(s1, d);
    }
    if ((t & 15) == 0) {
        int g0 = r0 + i0 - 1;
        if (g0 < NTOK) atomicAdd(&rsg[b * NTOK + g0], s0);
        if (t < 480 && g0 + 32 < NTOK) atomicAdd(&rsg[b * NTOK + g0 + 32], s1);
    }

    // ---- epilogue: partial O -> atomic ----
    #pragma unroll
    for (int p = 0; p < 2; ++p) {
        int rbase = 16 * (wti + p) + 4 * q4;
        #pragma unroll
        for (int r = 0; r < 4; ++r) {
            int i = rbase + r;
            int grow = r0 + i - 1;
            if (i >= 1 && i < 63 && grow < NTOK)
                atomicAdd(&outp[((size_t)(b * NTOK + grow) << 6) + 16 * wtj + m_], accO[p][r]);
        }
    }
}

// ---------------- Kernel 3: normalize out /= (rowsum + eps), in place ----------------
__global__ __launch_bounds__(256) void k_norm(float* __restrict__ out,
                                              const float* __restrict__ rsg) {
    int gid = blockIdx.x * 256 + threadIdx.x;   // 524288 float4s
    float4 o = ((float4*)out)[gid];
    float d = rsg[gid >> 4] + 1e-5f;
    float inv = 1.f / d;
    o.x *= inv; o.y *= inv; o.z *= inv; o.w *= inv;
    ((float4*)out)[gid] = o;
}

extern "C" void kernel_launch(void* const* d_in, const int* in_sizes, int n_in,
                              void* d_out, int out_size, void* d_ws, size_t ws_size,
                              hipStream_t stream) {
    const float* x  = (const float*)d_in[0];
    const float* Wq = (const float*)d_in[1];
    const float* bq = (const float*)d_in[2];
    const float* Wk = (const float*)d_in[3];
    const float* bk = (const float*)d_in[4];
    const float* Wv = (const float*)d_in[5];
    const float* bv = (const float*)d_in[6];
    const float* cw = (const float*)d_in[7];
    const float* cb = (const float*)d_in[8];
    float* out = (float*)d_out;

    char* ws = (char*)d_ws;
    bf16_t* wt = (bf16_t*)ws;                               // 98304 B
    bf16_t* qb = (bf16_t*)(ws + 98304);                     // 4 MB
    bf16_t* kb = (bf16_t*)(ws + 98304 + 4194304);           // 4 MB
    bf16_t* vt = (bf16_t*)(ws + 98304 + 8388608);           // 4 MB
    float*  rsg = (float*)(ws + 98304 + 12582912);          // 128 KB

    k_prep<<<dim3(1024), dim3(256), 0, stream>>>(Wq, Wk, Wv, wt, out, rsg);
    k_qkv<<<dim3(512), dim3(256), 0, stream>>>(x, wt, bq, bk, bv, qb, kb, vt);
    k_attn<<<dim3(34, 4, BQ), dim3(512), 0, stream>>>(qb, kb, vt, cw, cb, out, rsg);
    k_norm<<<dim3(2048), dim3(256), 0, stream>>>(out, rsg);
}

// Round 2
// 201.680 us; speedup vs baseline: 1.3765x; 1.3765x over previous
//
#include <hip/hip_runtime.h>
#include <hip/hip_bf16.h>

typedef __bf16 bf16_t;
typedef __bf16 bf16x8 __attribute__((ext_vector_type(8)));
typedef float  floatx4 __attribute__((ext_vector_type(4)));

#define BQ 16
#define NTOK 2048
#define DIM 256
#define HD 64

// ---------------- Kernel 0: W -> W^T bf16, + zero out-accumulator & rowsums ----------------
__global__ __launch_bounds__(256) void k_prep(const float* __restrict__ Wq,
                                              const float* __restrict__ Wk,
                                              const float* __restrict__ Wv,
                                              bf16_t* __restrict__ wt,
                                              float* __restrict__ outz,
                                              float* __restrict__ rsz) {
    int o = blockIdx.x * 256 + threadIdx.x;   // grid 1024 -> o < 262144
    if (o < 49152) {
        int w = o >> 14;
        int r = o & 16383;
        int h = r >> 8;
        int d = r & 255;
        const float* W = (w == 0) ? Wq : ((w == 1) ? Wk : Wv);
        wt[o] = (bf16_t)W[d * 64 + h];
    }
    // zero out (524288 float4) + rs (8192 float4)
    float4 z = make_float4(0.f, 0.f, 0.f, 0.f);
    for (int u = o; u < 532480; u += 262144) {
        if (u < 524288) ((float4*)outz)[u] = z;
        else            ((float4*)rsz)[u - 524288] = z;
    }
}

// ---------------- Kernel 1: QKV projection (64 tokens/block, 512 blocks) ----------------
#define XS 264
__global__ __launch_bounds__(256) void k_qkv(const float* __restrict__ x,
                                             const bf16_t* __restrict__ wt,
                                             const float* __restrict__ bq,
                                             const float* __restrict__ bk,
                                             const float* __restrict__ bv,
                                             bf16_t* __restrict__ qb,
                                             bf16_t* __restrict__ kb,
                                             bf16_t* __restrict__ vt) {
    __shared__ bf16_t x_ls[64 * XS];
    __shared__ bf16_t vt_ls[64 * 72];

    int b  = blockIdx.x >> 5;
    int t0 = (blockIdx.x & 31) << 6;
    int t  = threadIdx.x;
    int lane = t & 63;
    int w    = t >> 6;
    int m_   = lane & 15;
    int q4   = lane >> 4;

    for (int tau = t; tau < 4096; tau += 256) {
        int row = tau >> 6, ch = tau & 63;
        float4 v = ((const float4*)x)[(size_t)(b * NTOK + t0 + row) * 64 + ch];
        bf16_t tmp[4] = {(bf16_t)v.x, (bf16_t)v.y, (bf16_t)v.z, (bf16_t)v.w};
        *(uint2*)(&x_ls[row * XS + ch * 4]) = *(uint2*)tmp;
    }
    __syncthreads();

    for (int wi = 0; wi < 3; ++wi) {
        const bf16_t* wtw = wt + wi * 16384;
        floatx4 acc[4];
        #pragma unroll
        for (int mt = 0; mt < 4; ++mt) acc[mt] = floatx4{0.f, 0.f, 0.f, 0.f};

        #pragma unroll
        for (int ks = 0; ks < 8; ++ks) {
            bf16x8 bfrag = *(const bf16x8*)(wtw + (16 * w + m_) * 256 + ks * 32 + q4 * 8);
            #pragma unroll
            for (int mt = 0; mt < 4; ++mt) {
                bf16x8 afrag = *(const bf16x8*)(&x_ls[(16 * mt + m_) * XS + ks * 32 + q4 * 8]);
                acc[mt] = __builtin_amdgcn_mfma_f32_16x16x32_bf16(afrag, bfrag, acc[mt], 0, 0, 0);
            }
        }
        const float* bias_p = (wi == 0) ? bq : ((wi == 1) ? bk : bv);
        float bias = bias_p[16 * w + m_];
        float scale = (wi == 0) ? 0.125f : 1.0f;   // fold H^-0.5 into q (exact pow2)

        if (wi < 2) {
            bf16_t* dst = (wi == 0) ? qb : kb;
            #pragma unroll
            for (int mt = 0; mt < 4; ++mt)
                #pragma unroll
                for (int r = 0; r < 4; ++r) {
                    int tok = t0 + 16 * mt + 4 * q4 + r;
                    dst[(size_t)(b * NTOK + tok) * 64 + 16 * w + m_] = (bf16_t)((acc[mt][r] + bias) * scale);
                }
        } else {
            #pragma unroll
            for (int mt = 0; mt < 4; ++mt)
                #pragma unroll
                for (int r = 0; r < 4; ++r)
                    vt_ls[(16 * w + m_) * 72 + 16 * mt + 4 * q4 + r] = (bf16_t)(acc[mt][r] + bias);
            __syncthreads();
            for (int tau = t; tau < 512; tau += 256) {
                int h = tau >> 3, ch = tau & 7;
                uint4 val = *(const uint4*)(&vt_ls[h * 72 + ch * 8]);
                *(uint4*)(vt + (size_t)(b * 64 + h) * NTOK + t0 + ch * 8) = val;
            }
        }
    }
}

// ---------------- Kernel 2: fused attention, 64x64 frame (62x62 interior), 512 threads ----------------
#define SA 68     // A_ls fp32 stride (cols 64..67 zero pad, 16B-aligned rows)
#define SP 72     // bf16 LDS stride
#define RINT 62
#define L2E 1.44269504f

static __device__ __forceinline__ bf16x8 as_bf16x8(uint4 u) {
    union { uint4 a; bf16x8 b; } c; c.a = u; return c.b;
}

// NOTE: no min-waves arg. Round-1's "(512, 6)" made hipcc budget ~40 VGPRs
// (it budgets blocks/CU, not waves/EU, for 512-thr blocks) -> ~30 regs/thread
// spilled to scratch -> +280 MB HBM r/w per launch (FETCH 160/WRITE 185 MB).
__global__ __launch_bounds__(512) void k_attn(const bf16_t* __restrict__ qb,
                                              const bf16_t* __restrict__ kb,
                                              const bf16_t* __restrict__ vt,
                                              const float* __restrict__ conv_w,
                                              const float* __restrict__ conv_b,
                                              float* __restrict__ outp,
                                              float* __restrict__ rsg) {
    __shared__ bf16_t k_ls[64 * SP];   // 9216 B  [frame col j][ch]
    __shared__ bf16_t v_ls[64 * SP];   // 9216 B  [h][k], k = global_col - c0; cols 62/63 unused by PV (P=0 there)
    __shared__ bf16_t p_ls[64 * SP];   // 9216 B  [i][k]; rows 0,63 & k>=62 zero
    __shared__ float  A_ls[64 * SA];   // 17408 B  -> total 45056 B -> 3 blocks/CU LDS-wise

    int b  = blockIdx.z;
    int r0 = blockIdx.x * RINT;
    int it_beg = (int)(blockIdx.y * 34) >> 2;         // chunks {8,9,8,9} iters
    int it_end = (int)((blockIdx.y + 1) * 34) >> 2;

    int t = threadIdx.x, lane = t & 63, w = t >> 6;
    int m_ = lane & 15, q4 = lane >> 4;
    int wtj = w & 3;             // col tile 0..3
    int wti = (w >> 2) << 1;     // row tile base {0,2}

    const uint* vt32 = (const uint*)vt + (size_t)b * 64 * 1024;

    uint4 kreg;
    uint  vreg[4];
    // V staging: 2048 uint tasks (64 rows x 32), power-of-2 indexing, no predicates.
    // Task c==31 loads rim col (frame col 62/63) -> harmless: P cols 62/63 are always 0.
    auto prefetch = [&](int c0) {
        {
            int row = t >> 3, ch = t & 7;
            int g = c0 - 1 + row;
            uint4 val = make_uint4(0u, 0u, 0u, 0u);
            if (g >= 0 && g < NTOK)
                val = *(const uint4*)(kb + (size_t)(b * NTOK + g) * 64 + ch * 8);
            kreg = val;
        }
        #pragma unroll
        for (int j = 0; j < 4; ++j) {
            int tau = t + 512 * j;
            int n = c0 + 2 * (tau & 31);
            uint val = 0u;
            if (n < NTOK) val = vt32[(tau >> 5) * 1024 + (n >> 1)];
            vreg[j] = val;
        }
    };

    prefetch(it_beg * RINT);

    // conv weights, ln2-folded so sigmoid uses exp2 directly
    float cw[9];
    #pragma unroll
    for (int i = 0; i < 9; ++i) cw[i] = conv_w[i] * L2E;
    float cb = conv_b[0] * L2E;

    // Q fragments -> registers (frame rows 16*(wti+p)+m_, loaded once)
    bf16x8 qreg[2][2];
    #pragma unroll
    for (int p = 0; p < 2; ++p) {
        int g = r0 - 1 + 16 * (wti + p) + m_;
        #pragma unroll
        for (int ks = 0; ks < 2; ++ks) {
            uint4 val = make_uint4(0u, 0u, 0u, 0u);
            if (g >= 0 && g < NTOK)
                val = *(const uint4*)(qb + (size_t)(b * NTOK + g) * 64 + ks * 32 + q4 * 8);
            qreg[p][ks] = as_bf16x8(val);
        }
    }

    // one-time zero inits
    for (int u = t; u < 2304; u += 512) ((uint*)p_ls)[u] = 0u;              // whole p_ls
    if (t < 256) A_ls[(t >> 2) * SA + 64 + (t & 3)] = 0.f;                  // A_ls col pad (conv taps, must be finite 0)

    floatx4 accO[2];
    accO[0] = floatx4{0.f, 0.f, 0.f, 0.f};
    accO[1] = floatx4{0.f, 0.f, 0.f, 0.f};
    float rs[2] = {0.f, 0.f};

    int i0 = (t >> 4) + 1;     // conv row, round 0 (1..32); round 1 adds 32
    int gq = t & 15;           // quad col group 0..15
    int cvoff = (i0 - 1) * SA + 4 * gq;
    bool gq15 = (gq == 15);    // rim mask: frame col 4*gq+x valid iff <= 61

    for (int itg = it_beg; itg < it_end; ++itg) {
        // ---- regs -> LDS (k_ls, v_ls) ----
        {
            int row = t >> 3, ch = t & 7;
            *(uint4*)(&k_ls[row * SP + ch * 8]) = kreg;
            #pragma unroll
            for (int j = 0; j < 4; ++j) {
                int tau = t + 512 * j;
                *(uint*)(&v_ls[(tau >> 5) * SP + 2 * (tau & 31)]) = vreg[j];
            }
        }
        __syncthreads();

        // ---- QK^T: 16 tiles, 2 per wave, K=64, Q in registers ----
        #pragma unroll
        for (int p = 0; p < 2; ++p) {
            floatx4 a = floatx4{0.f, 0.f, 0.f, 0.f};
            #pragma unroll
            for (int ks = 0; ks < 2; ++ks) {
                bf16x8 bfr = *(const bf16x8*)(&k_ls[(16 * wtj + m_) * SP + ks * 32 + q4 * 8]);
                a = __builtin_amdgcn_mfma_f32_16x16x32_bf16(qreg[p][ks], bfr, a, 0, 0, 0);
            }
            int rbase = 16 * (wti + p) + 4 * q4;
            #pragma unroll
            for (int r = 0; r < 4; ++r)
                A_ls[(rbase + r) * SA + 16 * wtj + m_] = a[r];
        }
        __syncthreads();

        // issue next iter's global loads; latency overlaps conv below
        if (itg + 1 < it_end) prefetch((itg + 1) * RINT);

        // ---- conv + sigmoid + relu + expm1 (1x4 quads, 992 tasks over 2 rounds) ----
        #pragma unroll
        for (int round = 0; round < 2; ++round) {
            if (round == 0 || t < 480) {
                const float* base = &A_ls[cvoff + round * (32 * SA)];
                float a0[6], a1[6], a2[6];
                *(float4*)(a0)     = *(const float4*)(base);
                *(float2*)(a0 + 4) = *(const float2*)(base + 4);
                *(float4*)(a1)     = *(const float4*)(base + SA);
                *(float2*)(a1 + 4) = *(const float2*)(base + SA + 4);
                *(float4*)(a2)     = *(const float4*)(base + 2 * SA);
                *(float2*)(a2 + 4) = *(const float2*)(base + 2 * SA + 4);
                float esum = 0.f;
                bf16_t quad[4];
                #pragma unroll
                for (int x = 0; x < 4; ++x) {
                    float conv = cb
                        + cw[0] * a0[x] + cw[1] * a0[x + 1] + cw[2] * a0[x + 2]
                        + cw[3] * a1[x] + cw[4] * a1[x + 1] + cw[5] * a1[x + 2]
                        + cw[6] * a2[x] + cw[7] * a2[x + 1] + cw[8] * a2[x + 2];
                    float sig = __builtin_amdgcn_rcpf(1.f + __builtin_amdgcn_exp2f(-conv));
                    float s = fmaxf(a1[x + 1] - sig, 0.f);
                    float ev = __builtin_amdgcn_exp2f(s * L2E) - 1.f;
                    if (x >= 2) ev = gq15 ? 0.f : ev;     // frame cols 62,63 (rim) -> 0
                    quad[x] = (bf16_t)ev;
                    esum += ev;
                }
                rs[round] += esum;
                *(uint2*)(&p_ls[(i0 + round * 32) * SP + 4 * gq]) = *(uint2*)quad;
            }
        }
        __syncthreads();

        // ---- PV: O[64x64] += P @ V, 2 tiles per wave ----
        #pragma unroll
        for (int ks = 0; ks < 2; ++ks) {
            bf16x8 bfr = *(const bf16x8*)(&v_ls[(16 * wtj + m_) * SP + ks * 32 + q4 * 8]);
            #pragma unroll
            for (int p = 0; p < 2; ++p) {
                bf16x8 af = *(const bf16x8*)(&p_ls[(16 * (wti + p) + m_) * SP + ks * 32 + q4 * 8]);
                accO[p] = __builtin_amdgcn_mfma_f32_16x16x32_bf16(af, bfr, accO[p], 0, 0, 0);
            }
        }
        __syncthreads();
    }

    // ---- epilogue: rowsum via 16-lane shfl reduce -> atomic ----
    float s0 = rs[0], s1 = rs[1];
    #pragma unroll
    for (int d = 1; d < 16; d <<= 1) {
        s0 += __shfl_xor(s0, d);
        s1 += __shfl_xor(s1, d);
    }
    if ((t & 15) == 0) {
        int g0 = r0 + i0 - 1;
        if (g0 < NTOK) atomicAdd(&rsg[b * NTOK + g0], s0);
        if (t < 480 && g0 + 32 < NTOK) atomicAdd(&rsg[b * NTOK + g0 + 32], s1);
    }

    // ---- epilogue: partial O -> atomic ----
    #pragma unroll
    for (int p = 0; p < 2; ++p) {
        int rbase = 16 * (wti + p) + 4 * q4;
        #pragma unroll
        for (int r = 0; r < 4; ++r) {
            int i = rbase + r;
            int grow = r0 + i - 1;
            if (i >= 1 && i < 63 && grow < NTOK)
                atomicAdd(&outp[((size_t)(b * NTOK + grow) << 6) + 16 * wtj + m_], accO[p][r]);
        }
    }
}

// ---------------- Kernel 3: normalize out /= (rowsum + eps), in place ----------------
__global__ __launch_bounds__(256) void k_norm(float* __restrict__ out,
                                              const float* __restrict__ rsg) {
    int gid = blockIdx.x * 256 + threadIdx.x;   // 524288 float4s
    float4 o = ((float4*)out)[gid];
    float d = rsg[gid >> 4] + 1e-5f;
    float inv = 1.f / d;
    o.x *= inv; o.y *= inv; o.z *= inv; o.w *= inv;
    ((float4*)out)[gid] = o;
}

extern "C" void kernel_launch(void* const* d_in, const int* in_sizes, int n_in,
                              void* d_out, int out_size, void* d_ws, size_t ws_size,
                              hipStream_t stream) {
    const float* x  = (const float*)d_in[0];
    const float* Wq = (const float*)d_in[1];
    const float* bq = (const float*)d_in[2];
    const float* Wk = (const float*)d_in[3];
    const float* bk = (const float*)d_in[4];
    const float* Wv = (const float*)d_in[5];
    const float* bv = (const float*)d_in[6];
    const float* cw = (const float*)d_in[7];
    const float* cb = (const float*)d_in[8];
    float* out = (float*)d_out;

    char* ws = (char*)d_ws;
    bf16_t* wt = (bf16_t*)ws;                               // 98304 B
    bf16_t* qb = (bf16_t*)(ws + 98304);                     // 4 MB
    bf16_t* kb = (bf16_t*)(ws + 98304 + 4194304);           // 4 MB
    bf16_t* vt = (bf16_t*)(ws + 98304 + 8388608);           // 4 MB
    float*  rsg = (float*)(ws + 98304 + 12582912);          // 128 KB

    k_prep<<<dim3(1024), dim3(256), 0, stream>>>(Wq, Wk, Wv, wt, out, rsg);
    k_qkv<<<dim3(512), dim3(256), 0, stream>>>(x, wt, bq, bk, bv, qb, kb, vt);
    k_attn<<<dim3(34, 4, BQ), dim3(512), 0, stream>>>(qb, kb, vt, cw, cb, out, rsg);
    k_norm<<<dim3(2048), dim3(256), 0, stream>>>(out, rsg);
}